// Round 2
// baseline (2334.532 us; speedup 1.0000x reference)
//
#include <hip/hip_runtime.h>
#include <hip/hip_fp16.h>
#include <math.h>

#define BATCH 128
#define NTOK  343
#define CDIM  384
#define NH    12
#define DH    32
#define NWIN  32
#define MTOK  (BATCH*NTOK)   // 43904
#define NN    (NTOK*NTOK)    // 117649
#define QKVF  (3*CDIM)       // 1152
#define KSTR  36             // LDS row stride in halves (72B = 18 dwords: 2-way bank alias = free)

// ---------------- bias gather: bias_mat[h][i][j] = table[rel_index[i][j]][h] ----
__global__ __launch_bounds__(256) void bias_expand_k(
    const int* __restrict__ rel_index, const float* __restrict__ table,
    float* __restrict__ bias_mat) {
  int ij = blockIdx.x * 256 + threadIdx.x;
  if (ij >= NN) return;
  int idx = rel_index[ij];
#pragma unroll
  for (int h = 0; h < NH; ++h)
    bias_mat[(size_t)h * NN + ij] = table[idx * NH + h];
}

// ---------------- QKV GEMM: C[m,f] = sum_k x[m,k] * w_qkv[f,k], scatter to q/k/v (fp16)
__global__ __launch_bounds__(256) void gemm_qkv_k(
    const float* __restrict__ A, const float* __restrict__ W,
    __half* __restrict__ qb, __half* __restrict__ kb, __half* __restrict__ vb) {
  __shared__ float As[32][64];
  __shared__ float Ws[32][64];
  const int tid = threadIdx.x;
  const int tx = tid & 15, ty = tid >> 4;
  const int m0 = blockIdx.x * 64;
  const int f0 = blockIdx.y * 64;
  const int r  = tid >> 3, kq = (tid & 7) << 2;
  float acc[4][4] = {};
  for (int k0 = 0; k0 < CDIM; k0 += 32) {
    float4 a0 = *(const float4*)&A[(size_t)(m0 + r)      * CDIM + k0 + kq];
    float4 a1 = *(const float4*)&A[(size_t)(m0 + r + 32) * CDIM + k0 + kq];
    float4 w0 = *(const float4*)&W[(size_t)(f0 + r)      * CDIM + k0 + kq];
    float4 w1 = *(const float4*)&W[(size_t)(f0 + r + 32) * CDIM + k0 + kq];
    __syncthreads();
    As[kq+0][r]    = a0.x; As[kq+1][r]    = a0.y; As[kq+2][r]    = a0.z; As[kq+3][r]    = a0.w;
    As[kq+0][r+32] = a1.x; As[kq+1][r+32] = a1.y; As[kq+2][r+32] = a1.z; As[kq+3][r+32] = a1.w;
    Ws[kq+0][r]    = w0.x; Ws[kq+1][r]    = w0.y; Ws[kq+2][r]    = w0.z; Ws[kq+3][r]    = w0.w;
    Ws[kq+0][r+32] = w1.x; Ws[kq+1][r+32] = w1.y; Ws[kq+2][r+32] = w1.z; Ws[kq+3][r+32] = w1.w;
    __syncthreads();
#pragma unroll
    for (int k = 0; k < 32; ++k) {
      float a4[4], w4[4];
      *(float4*)a4 = *(const float4*)&As[k][ty*4];
      *(float4*)w4 = *(const float4*)&Ws[k][tx*4];
#pragma unroll
      for (int i = 0; i < 4; ++i)
#pragma unroll
        for (int j = 0; j < 4; ++j)
          acc[i][j] = fmaf(a4[i], w4[j], acc[i][j]);
    }
  }
  const float scale = 0.17677669529663687f;  // 32^-0.5
#pragma unroll
  for (int i = 0; i < 4; ++i) {
    int m = m0 + ty*4 + i;
    int b = m / NTOK;
    int t = m - b * NTOK;
#pragma unroll
    for (int j = 0; j < 4; ++j) {
      int f = f0 + tx*4 + j;
      int which = f / CDIM;
      int rem = f - which * CDIM;
      int h = rem >> 5, d = rem & 31;
      float v = acc[i][j];
      if (which == 0) v *= scale;
      __half* dst = (which == 0) ? qb : ((which == 1) ? kb : vb);
      dst[(((size_t)b * NH + h) * NTOK + t) * DH + d] = __float2half(v);
    }
  }
}

// ---------------- proj GEMM: out[m,f] = sum_k av[m,k](fp16) * w_proj[f,k] + b_proj[f]
__global__ __launch_bounds__(256) void gemm_proj_k(
    const __half* __restrict__ A, const float* __restrict__ W,
    const float* __restrict__ bias, float* __restrict__ out) {
  __shared__ float As[32][64];
  __shared__ float Ws[32][64];
  const int tid = threadIdx.x;
  const int tx = tid & 15, ty = tid >> 4;
  const int m0 = blockIdx.x * 64;
  const int f0 = blockIdx.y * 64;
  const int r  = tid >> 3, kq = (tid & 7) << 2;
  float acc[4][4] = {};
  for (int k0 = 0; k0 < CDIM; k0 += 32) {
    float2 a0r = *(const float2*)&A[(size_t)(m0 + r)      * CDIM + k0 + kq];
    float2 a1r = *(const float2*)&A[(size_t)(m0 + r + 32) * CDIM + k0 + kq];
    float4 w0 = *(const float4*)&W[(size_t)(f0 + r)      * CDIM + k0 + kq];
    float4 w1 = *(const float4*)&W[(size_t)(f0 + r + 32) * CDIM + k0 + kq];
    const __half2* h0 = (const __half2*)&a0r;
    const __half2* h1 = (const __half2*)&a1r;
    float2 f00 = __half22float2(h0[0]), f01 = __half22float2(h0[1]);
    float2 f10 = __half22float2(h1[0]), f11 = __half22float2(h1[1]);
    __syncthreads();
    As[kq+0][r]    = f00.x; As[kq+1][r]    = f00.y; As[kq+2][r]    = f01.x; As[kq+3][r]    = f01.y;
    As[kq+0][r+32] = f10.x; As[kq+1][r+32] = f10.y; As[kq+2][r+32] = f11.x; As[kq+3][r+32] = f11.y;
    Ws[kq+0][r]    = w0.x; Ws[kq+1][r]    = w0.y; Ws[kq+2][r]    = w0.z; Ws[kq+3][r]    = w0.w;
    Ws[kq+0][r+32] = w1.x; Ws[kq+1][r+32] = w1.y; Ws[kq+2][r+32] = w1.z; Ws[kq+3][r+32] = w1.w;
    __syncthreads();
#pragma unroll
    for (int k = 0; k < 32; ++k) {
      float a4[4], w4[4];
      *(float4*)a4 = *(const float4*)&As[k][ty*4];
      *(float4*)w4 = *(const float4*)&Ws[k][tx*4];
#pragma unroll
      for (int i = 0; i < 4; ++i)
#pragma unroll
        for (int j = 0; j < 4; ++j)
          acc[i][j] = fmaf(a4[i], w4[j], acc[i][j]);
    }
  }
#pragma unroll
  for (int i = 0; i < 4; ++i) {
    int m = m0 + ty*4 + i;
#pragma unroll
    for (int j = 0; j < 4; ++j) {
      int f = f0 + tx*4 + j;
      out[(size_t)m * CDIM + f] = acc[i][j] + bias[f];
    }
  }
}

// ---------------- attention: one block per (b,h); K,V fp16 in LDS; 2 query rows/wave
__global__ __launch_bounds__(256) void attn_k(
    const __half* __restrict__ qg, const __half* __restrict__ kg,
    const __half* __restrict__ vg, const float* __restrict__ bias_mat,
    const float* __restrict__ mask, __half* __restrict__ av) {
  __shared__ __half Ks[NTOK * KSTR];    // 24,696 B
  __shared__ __half Vs[NTOK * KSTR];    // 24,696 B
  __shared__ float  Ps[4][2][NTOK + 1]; // 11,008 B  -> total 60.4 KB

  const int bh = blockIdx.x;            // 0..1535
  const int b  = bh / NH;
  const int h  = bh - b * NH;
  const int w  = b & (NWIN - 1);        // b % 32
  const size_t base = (size_t)bh * NTOK * DH;

  // stage K, V (fp16, 8 halves per slot)
  for (int idx = threadIdx.x; idx < NTOK * 4; idx += 256) {
    int j = idx >> 2, dq = (idx & 3) << 3;
    float4 kv = *(const float4*)&kg[base + (size_t)j * DH + dq];
    float4 vv = *(const float4*)&vg[base + (size_t)j * DH + dq];
    *(float2*)&Ks[j * KSTR + dq]     = make_float2(kv.x, kv.y);
    *(float2*)&Ks[j * KSTR + dq + 4] = make_float2(kv.z, kv.w);
    *(float2*)&Vs[j * KSTR + dq]     = make_float2(vv.x, vv.y);
    *(float2*)&Vs[j * KSTR + dq + 4] = make_float2(vv.z, vv.w);
  }
  __syncthreads();

  const int wave = threadIdx.x >> 6, lane = threadIdx.x & 63;
  const float* bias_h = bias_mat + (size_t)h * NN;
  const float* mask_w = mask + (size_t)w * NN;

  for (int i0 = wave * 2; i0 < NTOK; i0 += 8) {
    const int  i1   = i0 + 1;
    const bool has1 = (i1 < NTOK);
    const int  i1c  = has1 ? i1 : i0;

    // q rows into registers (broadcast reads)
    float qa[32], qbv[32];
    {
      const __half* q0 = &qg[base + (size_t)i0  * DH];
      const __half* q1 = &qg[base + (size_t)i1c * DH];
#pragma unroll
      for (int dq = 0; dq < 32; dq += 8) {
        float4 r0 = *(const float4*)&q0[dq];
        float4 r1 = *(const float4*)&q1[dq];
        const __half2* h0 = (const __half2*)&r0;
        const __half2* h1 = (const __half2*)&r1;
#pragma unroll
        for (int u = 0; u < 4; ++u) {
          float2 f0 = __half22float2(h0[u]);
          float2 f1 = __half22float2(h1[u]);
          qa[dq + 2*u] = f0.x; qa[dq + 2*u + 1] = f0.y;
          qbv[dq + 2*u] = f1.x; qbv[dq + 2*u + 1] = f1.y;
        }
      }
    }
    // prefetch bias+mask for both rows
    float bm0[6], bm1[6];
#pragma unroll
    for (int t = 0; t < 6; ++t) {
      int j = t * 64 + lane;
      if (j < NTOK) {
        bm0[t] = bias_h[(size_t)i0  * NTOK + j] + mask_w[(size_t)i0  * NTOK + j];
        bm1[t] = bias_h[(size_t)i1c * NTOK + j] + mask_w[(size_t)i1c * NTOK + j];
      } else { bm0[t] = 0.f; bm1[t] = 0.f; }
    }

    // phase 1: scores (lane -> key j)
    float s0[6], s1[6];
#pragma unroll
    for (int t = 0; t < 6; ++t) {
      int j = t * 64 + lane;
      bool valid = (j < NTOK);
      int jc = valid ? j : 0;
      float acc0 = 0.f, acc1 = 0.f;
      const __half2* kr = (const __half2*)&Ks[jc * KSTR];
#pragma unroll
      for (int d2 = 0; d2 < 16; ++d2) {
        float2 kf = __half22float2(kr[d2]);
        acc0 = fmaf(qa[2*d2],    kf.x, acc0);
        acc0 = fmaf(qa[2*d2+1],  kf.y, acc0);
        acc1 = fmaf(qbv[2*d2],   kf.x, acc1);
        acc1 = fmaf(qbv[2*d2+1], kf.y, acc1);
      }
      s0[t] = valid ? (acc0 + bm0[t]) : -1e30f;
      s1[t] = valid ? (acc1 + bm1[t]) : -1e30f;
    }

    // phase 2: softmax (register + butterfly)
    float m0v = -1e30f, m1v = -1e30f;
#pragma unroll
    for (int t = 0; t < 6; ++t) { m0v = fmaxf(m0v, s0[t]); m1v = fmaxf(m1v, s1[t]); }
#pragma unroll
    for (int off = 32; off >= 1; off >>= 1) {
      m0v = fmaxf(m0v, __shfl_xor(m0v, off));
      m1v = fmaxf(m1v, __shfl_xor(m1v, off));
    }
    float sum0 = 0.f, sum1 = 0.f;
#pragma unroll
    for (int t = 0; t < 6; ++t) {
      int j = t * 64 + lane;
      float p0 = expf(s0[t] - m0v);
      float p1 = expf(s1[t] - m1v);
      if (j < NTOK) {
        Ps[wave][0][j] = p0; Ps[wave][1][j] = p1;
        sum0 += p0; sum1 += p1;
      }
    }
#pragma unroll
    for (int off = 32; off >= 1; off >>= 1) {
      sum0 += __shfl_xor(sum0, off);
      sum1 += __shfl_xor(sum1, off);
    }
    float inv0 = 1.f / sum0, inv1 = 1.f / sum1;

    // phase 3: PV (lane -> (d-quad, j-slice))
    const int dg = lane & 7, js = lane >> 3;
    const int d0 = dg * 4;
    float o0[4] = {0.f,0.f,0.f,0.f}, o1[4] = {0.f,0.f,0.f,0.f};
    for (int j = js; j < NTOK; j += 8) {
      float p0 = Ps[wave][0][j];
      float p1 = Ps[wave][1][j];
      const __half2* vr = (const __half2*)&Vs[j * KSTR + d0];
      float2 v01 = __half22float2(vr[0]);
      float2 v23 = __half22float2(vr[1]);
      o0[0] = fmaf(p0, v01.x, o0[0]); o0[1] = fmaf(p0, v01.y, o0[1]);
      o0[2] = fmaf(p0, v23.x, o0[2]); o0[3] = fmaf(p0, v23.y, o0[3]);
      o1[0] = fmaf(p1, v01.x, o1[0]); o1[1] = fmaf(p1, v01.y, o1[1]);
      o1[2] = fmaf(p1, v23.x, o1[2]); o1[3] = fmaf(p1, v23.y, o1[3]);
    }
#pragma unroll
    for (int off = 8; off < 64; off <<= 1) {
#pragma unroll
      for (int c = 0; c < 4; ++c) {
        o0[c] += __shfl_xor(o0[c], off);
        o1[c] += __shfl_xor(o1[c], off);
      }
    }
    if (js == 0) {
      size_t obase = ((size_t)b * NTOK + i0) * CDIM + h * DH + d0;
      __half2 r01 = __floats2half2_rn(o0[0]*inv0, o0[1]*inv0);
      __half2 r23 = __floats2half2_rn(o0[2]*inv0, o0[3]*inv0);
      *(__half2*)&av[obase]     = r01;
      *(__half2*)&av[obase + 2] = r23;
      if (has1) {
        __half2 s01 = __floats2half2_rn(o1[0]*inv1, o1[1]*inv1);
        __half2 s23 = __floats2half2_rn(o1[2]*inv1, o1[3]*inv1);
        *(__half2*)&av[obase + CDIM]     = s01;
        *(__half2*)&av[obase + CDIM + 2] = s23;
      }
    }
  }
}

extern "C" void kernel_launch(void* const* d_in, const int* in_sizes, int n_in,
                              void* d_out, int out_size, void* d_ws, size_t ws_size,
                              hipStream_t stream) {
  const float* x          = (const float*)d_in[0];
  const float* mask       = (const float*)d_in[4];
  const float* w_qkv      = (const float*)d_in[6];
  const float* bias_table = (const float*)d_in[7];
  const float* w_proj     = (const float*)d_in[8];
  const float* b_proj     = (const float*)d_in[9];
  const int*   rel_index  = (const int*)d_in[10];
  float* out = (float*)d_out;

  // workspace (fp16 q,k,v,av + fp32 bias_mat): 4*33.7MB + 5.6MB = 140.5 MB
  __half* ws16 = (__half*)d_ws;
  const size_t SZ = (size_t)MTOK * CDIM;  // 16,859,136 halves per buffer
  __half* qbuf  = ws16;
  __half* kbuf  = qbuf + SZ;
  __half* vbuf  = kbuf + SZ;
  __half* avbuf = vbuf + SZ;
  float*  bias_mat = (float*)(avbuf + SZ);

  bias_expand_k<<<(NN + 255) / 256, 256, 0, stream>>>(rel_index, bias_table, bias_mat);
  gemm_qkv_k<<<dim3(MTOK / 64, QKVF / 64), 256, 0, stream>>>(x, w_qkv, qbuf, kbuf, vbuf);
  attn_k<<<BATCH * NH, 256, 0, stream>>>(qbuf, kbuf, vbuf, bias_mat, mask, avbuf);
  gemm_proj_k<<<dim3(MTOK / 64, CDIM / 64), 256, 0, stream>>>(avbuf, w_proj, b_proj, out);
}

// Round 3
// 953.491 us; speedup vs baseline: 2.4484x; 2.4484x over previous
//
#include <hip/hip_runtime.h>
#include <hip/hip_fp16.h>
#include <math.h>

#define BATCH 128
#define NTOK  343
#define NPAD  352
#define CDIM  384
#define NH    12
#define DH    32
#define NWIN  32
#define MTOK  (BATCH*NTOK)   // 43904
#define NN    (NTOK*NTOK)    // 117649
#define QKVF  (3*CDIM)       // 1152
#define KSTR  40             // K LDS row stride (halves): 80 B, 2-way bank alias (free)
#define VSTR  360            // Vt/P LDS row stride (halves): 720 B, perfect 2-way tiling
#define PSTR  360
#define MBW   11             // u32 words per packed mask row (343 bits)

typedef float    f32x4 __attribute__((ext_vector_type(4)));
typedef _Float16 half8 __attribute__((ext_vector_type(8)));

#define LDS_K   (NPAD*KSTR)                 // 14080 halves = 28160 B
#define LDS_V   (DH*VSTR)                   // 11520 halves = 23040 B
#define LDS_P   (16*PSTR)                   // per-wave 5760 halves = 11520 B
#define LDS_TOT (LDS_K + LDS_V + 8*LDS_P)   // 71680 halves = 143360 B

// ---------------- bias gather to fp16 dense [h][i][j] ----------------
__global__ __launch_bounds__(256) void bias_expand_k(
    const int* __restrict__ rel_index, const float* __restrict__ table,
    __half* __restrict__ bias16) {
  int ij = blockIdx.x * 256 + threadIdx.x;
  if (ij >= NN) return;
  int idx = rel_index[ij];
#pragma unroll
  for (int hh = 0; hh < NH; ++hh)
    bias16[(size_t)hh * NN + ij] = __float2half(table[idx * NH + hh]);
}

// ---------------- mask bit-pack: bit=1 where mask==0 (allowed) ----------------
__global__ __launch_bounds__(256) void mask_pack_k(
    const float* __restrict__ mask, unsigned int* __restrict__ mbits) {
  int row = blockIdx.x * 4 + (threadIdx.x >> 6);   // row = w*NTOK + i
  int lane = threadIdx.x & 63;
  if (row >= NWIN * NTOK) return;
  const float* mr = mask + (size_t)row * NTOK;
#pragma unroll
  for (int seg = 0; seg < 6; ++seg) {
    int j = seg * 64 + lane;
    bool allowed = (j < NTOK) ? (mr[j] == 0.0f) : false;
    unsigned long long bits = __ballot(allowed);
    if (lane == 0) mbits[(size_t)row * MBW + seg*2] = (unsigned)bits;
    if (lane == 1 && seg*2 + 1 < MBW) mbits[(size_t)row * MBW + seg*2 + 1] = (unsigned)(bits >> 32);
  }
}

// ---------------- QKV GEMM (unchanged, known-good): fp32 in, fp16 q/k/v out ----
__global__ __launch_bounds__(256) void gemm_qkv_k(
    const float* __restrict__ A, const float* __restrict__ W,
    __half* __restrict__ qb, __half* __restrict__ kb, __half* __restrict__ vb) {
  __shared__ float As[32][64];
  __shared__ float Ws[32][64];
  const int tid = threadIdx.x;
  const int tx = tid & 15, ty = tid >> 4;
  const int m0 = blockIdx.x * 64;
  const int f0 = blockIdx.y * 64;
  const int r  = tid >> 3, kq = (tid & 7) << 2;
  float acc[4][4] = {};
  for (int k0 = 0; k0 < CDIM; k0 += 32) {
    float4 a0 = *(const float4*)&A[(size_t)(m0 + r)      * CDIM + k0 + kq];
    float4 a1 = *(const float4*)&A[(size_t)(m0 + r + 32) * CDIM + k0 + kq];
    float4 w0 = *(const float4*)&W[(size_t)(f0 + r)      * CDIM + k0 + kq];
    float4 w1 = *(const float4*)&W[(size_t)(f0 + r + 32) * CDIM + k0 + kq];
    __syncthreads();
    As[kq+0][r]    = a0.x; As[kq+1][r]    = a0.y; As[kq+2][r]    = a0.z; As[kq+3][r]    = a0.w;
    As[kq+0][r+32] = a1.x; As[kq+1][r+32] = a1.y; As[kq+2][r+32] = a1.z; As[kq+3][r+32] = a1.w;
    Ws[kq+0][r]    = w0.x; Ws[kq+1][r]    = w0.y; Ws[kq+2][r]    = w0.z; Ws[kq+3][r]    = w0.w;
    Ws[kq+0][r+32] = w1.x; Ws[kq+1][r+32] = w1.y; Ws[kq+2][r+32] = w1.z; Ws[kq+3][r+32] = w1.w;
    __syncthreads();
#pragma unroll
    for (int k = 0; k < 32; ++k) {
      float a4[4], w4[4];
      *(float4*)a4 = *(const float4*)&As[k][ty*4];
      *(float4*)w4 = *(const float4*)&Ws[k][tx*4];
#pragma unroll
      for (int i = 0; i < 4; ++i)
#pragma unroll
        for (int j = 0; j < 4; ++j)
          acc[i][j] = fmaf(a4[i], w4[j], acc[i][j]);
    }
  }
  const float scale = 0.17677669529663687f;  // 32^-0.5
#pragma unroll
  for (int i = 0; i < 4; ++i) {
    int m = m0 + ty*4 + i;
    int b = m / NTOK;
    int t = m - b * NTOK;
#pragma unroll
    for (int j = 0; j < 4; ++j) {
      int f = f0 + tx*4 + j;
      int which = f / CDIM;
      int rem = f - which * CDIM;
      int h = rem >> 5, d = rem & 31;
      float v = acc[i][j];
      if (which == 0) v *= scale;
      __half* dst = (which == 0) ? qb : ((which == 1) ? kb : vb);
      dst[(((size_t)b * NH + h) * NTOK + t) * DH + d] = __float2half(v);
    }
  }
}

// ---------------- proj GEMM (unchanged, known-good) ----------------
__global__ __launch_bounds__(256) void gemm_proj_k(
    const __half* __restrict__ A, const float* __restrict__ W,
    const float* __restrict__ bias, float* __restrict__ out) {
  __shared__ float As[32][64];
  __shared__ float Ws[32][64];
  const int tid = threadIdx.x;
  const int tx = tid & 15, ty = tid >> 4;
  const int m0 = blockIdx.x * 64;
  const int f0 = blockIdx.y * 64;
  const int r  = tid >> 3, kq = (tid & 7) << 2;
  float acc[4][4] = {};
  for (int k0 = 0; k0 < CDIM; k0 += 32) {
    float2 a0r = *(const float2*)&A[(size_t)(m0 + r)      * CDIM + k0 + kq];
    float2 a1r = *(const float2*)&A[(size_t)(m0 + r + 32) * CDIM + k0 + kq];
    float4 w0 = *(const float4*)&W[(size_t)(f0 + r)      * CDIM + k0 + kq];
    float4 w1 = *(const float4*)&W[(size_t)(f0 + r + 32) * CDIM + k0 + kq];
    const __half2* h0 = (const __half2*)&a0r;
    const __half2* h1 = (const __half2*)&a1r;
    float2 f00 = __half22float2(h0[0]), f01 = __half22float2(h0[1]);
    float2 f10 = __half22float2(h1[0]), f11 = __half22float2(h1[1]);
    __syncthreads();
    As[kq+0][r]    = f00.x; As[kq+1][r]    = f00.y; As[kq+2][r]    = f01.x; As[kq+3][r]    = f01.y;
    As[kq+0][r+32] = f10.x; As[kq+1][r+32] = f10.y; As[kq+2][r+32] = f11.x; As[kq+3][r+32] = f11.y;
    Ws[kq+0][r]    = w0.x; Ws[kq+1][r]    = w0.y; Ws[kq+2][r]    = w0.z; Ws[kq+3][r]    = w0.w;
    Ws[kq+0][r+32] = w1.x; Ws[kq+1][r+32] = w1.y; Ws[kq+2][r+32] = w1.z; Ws[kq+3][r+32] = w1.w;
    __syncthreads();
#pragma unroll
    for (int k = 0; k < 32; ++k) {
      float a4[4], w4[4];
      *(float4*)a4 = *(const float4*)&As[k][ty*4];
      *(float4*)w4 = *(const float4*)&Ws[k][tx*4];
#pragma unroll
      for (int i = 0; i < 4; ++i)
#pragma unroll
        for (int j = 0; j < 4; ++j)
          acc[i][j] = fmaf(a4[i], w4[j], acc[i][j]);
    }
  }
#pragma unroll
  for (int i = 0; i < 4; ++i) {
    int m = m0 + ty*4 + i;
#pragma unroll
    for (int j = 0; j < 4; ++j) {
      int f = f0 + tx*4 + j;
      out[(size_t)m * CDIM + f] = acc[i][j] + bias[f];
    }
  }
}

// ---------------- MFMA attention: 1 block per (b,h), 8 waves, wave-per-Q-tile ----
__global__ __launch_bounds__(512, 1) void attn_k(
    const __half* __restrict__ qg, const __half* __restrict__ kg,
    const __half* __restrict__ vg, const __half* __restrict__ bias16,
    const unsigned int* __restrict__ mbits, __half* __restrict__ av) {
  extern __shared__ __half smem[];
  __half* Ks = smem;                 // [NPAD][KSTR]
  __half* Vt = smem + LDS_K;         // [DH][VSTR] (transposed V)
  const int tid  = threadIdx.x;
  const int wave = tid >> 6, lane = tid & 63;
  const int lr   = lane & 15, lg = lane >> 4;
  __half* Pw = smem + LDS_K + LDS_V + wave * LDS_P;  // per-wave [16][PSTR]

  const int bh = blockIdx.x;
  const int b  = bh / NH, h = bh - b * NH;
  const int w  = b & (NWIN - 1);
  const size_t base = (size_t)bh * NTOK * DH;

  // stage K (rows >= NTOK zeroed)
  for (int idx = tid; idx < NPAD * 4; idx += 512) {
    int j = idx >> 2, off = (idx & 3) << 3;
    half8 val = {0,0,0,0,0,0,0,0};
    if (j < NTOK) val = *reinterpret_cast<const half8*>(&kg[base + (size_t)j * DH + off]);
    *reinterpret_cast<half8*>(&Ks[j * KSTR + off]) = val;
  }
  // stage V transposed (cols >= NTOK zeroed -- NaN guard)
  for (int idx = tid; idx < NPAD * 4; idx += 512) {
    int j = idx >> 2, off = (idx & 3) << 3;
    if (j < NTOK) {
      union { float4 f; __half h[8]; } u;
      u.f = *reinterpret_cast<const float4*>(&vg[base + (size_t)j * DH + off]);
#pragma unroll
      for (int uu = 0; uu < 8; ++uu) Vt[(off + uu) * VSTR + j] = u.h[uu];
    } else {
#pragma unroll
      for (int uu = 0; uu < 8; ++uu) Vt[(off + uu) * VSTR + j] = __float2half(0.f);
    }
  }
  __syncthreads();

  const __half* bias_h = bias16 + (size_t)h * NN;
  const unsigned int* mb_w = mbits + (size_t)w * NTOK * MBW;

  for (int i0 = wave * 16; i0 < NPAD; i0 += 128) {
    // Q A-frag: Q[i0+lr][lg*8 .. +7], row-clamped for padded rows
    int qrow = min(i0 + lr, NTOK - 1);
    half8 qa = *reinterpret_cast<const half8*>(&qg[base + (size_t)qrow * DH + lg * 8]);

    // QK^T: 22 j-tiles, one MFMA each (K=32 complete)
    f32x4 s[22];
    const f32x4 zf = {0.f, 0.f, 0.f, 0.f};
#pragma unroll
    for (int jt = 0; jt < 22; ++jt) {
      half8 kb = *reinterpret_cast<const half8*>(&Ks[(jt * 16 + lr) * KSTR + lg * 8]);
      s[jt] = __builtin_amdgcn_mfma_f32_16x16x32_f16(qa, kb, zf, 0, 0, 0);
    }

    int il[4];
#pragma unroll
    for (int r = 0; r < 4; ++r) il[r] = min(i0 + lg * 4 + r, NTOK - 1);

    // fused bias + mask + j-validity (D layout: row i=(lg*4+r), col j=jt*16+lr)
#pragma unroll
    for (int jt = 0; jt < 22; ++jt) {
      int j = jt * 16 + lr;
      bool vj = (jt < 21) || (lr < 7);          // j < 343
      int jl = vj ? j : (NTOK - 1);
      unsigned sh = (unsigned)(((jt & 1) << 4) + lr);
#pragma unroll
      for (int r = 0; r < 4; ++r) {
        float bm = __half2float(bias_h[(size_t)il[r] * NTOK + jl]);
        unsigned mwv = mb_w[il[r] * MBW + (jt >> 1)];   // broadcast within 16-lane group
        float madd = ((mwv >> sh) & 1u) ? 0.f : -100.f;
        float val = s[jt][r] + bm + madd;
        s[jt][r] = vj ? val : -1e30f;
      }
    }

    // softmax: per-lane partial over 22 regs, then 16-lane butterfly (bits 0-3 only)
    float mx[4] = {-1e30f, -1e30f, -1e30f, -1e30f};
#pragma unroll
    for (int jt = 0; jt < 22; ++jt)
#pragma unroll
      for (int r = 0; r < 4; ++r) mx[r] = fmaxf(mx[r], s[jt][r]);
#pragma unroll
    for (int off = 1; off <= 8; off <<= 1)
#pragma unroll
      for (int r = 0; r < 4; ++r) mx[r] = fmaxf(mx[r], __shfl_xor(mx[r], off));
    float sm[4] = {0.f, 0.f, 0.f, 0.f};
#pragma unroll
    for (int jt = 0; jt < 22; ++jt)
#pragma unroll
      for (int r = 0; r < 4; ++r) {
        float p = __expf(s[jt][r] - mx[r]);
        s[jt][r] = p;
        sm[r] += p;
      }
#pragma unroll
    for (int off = 1; off <= 8; off <<= 1)
#pragma unroll
      for (int r = 0; r < 4; ++r) sm[r] += __shfl_xor(sm[r], off);

    // P -> LDS (fp16, unnormalized; scale output by 1/sum instead)
#pragma unroll
    for (int jt = 0; jt < 22; ++jt)
#pragma unroll
      for (int r = 0; r < 4; ++r)
        Pw[(lg * 4 + r) * PSTR + jt * 16 + lr] = __float2half(s[jt][r]);
    asm volatile("s_waitcnt lgkmcnt(0)" ::: "memory");
    __builtin_amdgcn_sched_barrier(0);

    // PV: O[16 x 32], K-dim = 352 in 11 chunks of 32
    f32x4 o0 = {0.f, 0.f, 0.f, 0.f}, o1 = {0.f, 0.f, 0.f, 0.f};
#pragma unroll
    for (int kt = 0; kt < 11; ++kt) {
      half8 pa  = *reinterpret_cast<const half8*>(&Pw[lr * PSTR + kt * 32 + lg * 8]);
      half8 vb0 = *reinterpret_cast<const half8*>(&Vt[lr * VSTR + kt * 32 + lg * 8]);
      half8 vb1 = *reinterpret_cast<const half8*>(&Vt[(16 + lr) * VSTR + kt * 32 + lg * 8]);
      o0 = __builtin_amdgcn_mfma_f32_16x16x32_f16(pa, vb0, o0, 0, 0, 0);
      o1 = __builtin_amdgcn_mfma_f32_16x16x32_f16(pa, vb1, o1, 0, 0, 0);
    }

    // store (D layout: i = i0+lg*4+r, d = {lr, 16+lr}); inv-sum matches row map
#pragma unroll
    for (int r = 0; r < 4; ++r) {
      int i = i0 + lg * 4 + r;
      if (i < NTOK) {
        float inv = 1.f / sm[r];
        size_t ob = ((size_t)b * NTOK + i) * CDIM + h * DH;
        av[ob + lr]      = __float2half(o0[r] * inv);
        av[ob + 16 + lr] = __float2half(o1[r] * inv);
      }
    }
  }
}

extern "C" void kernel_launch(void* const* d_in, const int* in_sizes, int n_in,
                              void* d_out, int out_size, void* d_ws, size_t ws_size,
                              hipStream_t stream) {
  const float* x          = (const float*)d_in[0];
  const float* mask       = (const float*)d_in[4];
  const float* w_qkv      = (const float*)d_in[6];
  const float* bias_table = (const float*)d_in[7];
  const float* w_proj     = (const float*)d_in[8];
  const float* b_proj     = (const float*)d_in[9];
  const int*   rel_index  = (const int*)d_in[10];
  float* out = (float*)d_out;

  // ws: 4 fp16 [MTOK*CDIM] buffers + fp16 bias[12][343][343] + u32 mask bits
  // = 134.87 MB + 2.82 MB + 0.48 MB = 138.2 MB (< round-2's proven 140.5 MB)
  __half* ws16 = (__half*)d_ws;
  const size_t SZ = (size_t)MTOK * CDIM;
  __half* qbuf  = ws16;
  __half* kbuf  = qbuf + SZ;
  __half* vbuf  = kbuf + SZ;
  __half* avbuf = vbuf + SZ;
  __half* bias16 = avbuf + SZ;
  unsigned int* mbits = (unsigned int*)(bias16 + (size_t)NH * NN);

  mask_pack_k<<<(NWIN * NTOK + 3) / 4, 256, 0, stream>>>(mask, mbits);
  bias_expand_k<<<(NN + 255) / 256, 256, 0, stream>>>(rel_index, bias_table, bias16);
  gemm_qkv_k<<<dim3(MTOK / 64, QKVF / 64), 256, 0, stream>>>(x, w_qkv, qbuf, kbuf, vbuf);

  (void)hipFuncSetAttribute((const void*)attn_k,
                            hipFuncAttributeMaxDynamicSharedMemorySize, LDS_TOT * 2);
  attn_k<<<BATCH * NH, 512, LDS_TOT * 2, stream>>>(qbuf, kbuf, vbuf, bias16, mbits, avbuf);

  gemm_proj_k<<<dim3(MTOK / 64, CDIM / 64), 256, 0, stream>>>(avbuf, w_proj, b_proj, out);
}

// Round 4
// 389.948 us; speedup vs baseline: 5.9868x; 2.4452x over previous
//
#include <hip/hip_runtime.h>
#include <hip/hip_fp16.h>
#include <math.h>

#define BATCH 128
#define NTOK  343
#define NPAD  352
#define CDIM  384
#define NH    12
#define DH    32
#define NWIN  32
#define MTOK  (BATCH*NTOK)   // 43904
#define NN    (NTOK*NTOK)    // 117649
#define QKVF  (3*CDIM)       // 1152
#define KSTR  40             // attn K LDS row stride (halves)
#define VSTR  360
#define PSTR  360
#define MBW   11             // u32 words per packed mask row

typedef float    f32x4 __attribute__((ext_vector_type(4)));
typedef _Float16 half8 __attribute__((ext_vector_type(8)));

#define LDS_K   (NPAD*KSTR)
#define LDS_V   (DH*VSTR)
#define LDS_P   (16*PSTR)
#define LDS_TOT (LDS_K + LDS_V + 8*LDS_P)   // 143360 B

// ---------------- bias gather to fp16 dense [h][i][j] ----------------
__global__ __launch_bounds__(256) void bias_expand_k(
    const int* __restrict__ rel_index, const float* __restrict__ table,
    __half* __restrict__ bias16) {
  int ij = blockIdx.x * 256 + threadIdx.x;
  if (ij >= NN) return;
  int idx = rel_index[ij];
#pragma unroll
  for (int hh = 0; hh < NH; ++hh)
    bias16[(size_t)hh * NN + ij] = __float2half(table[idx * NH + hh]);
}

// ---------------- mask bit-pack: bit=1 where mask==0 (allowed) ----------------
__global__ __launch_bounds__(256) void mask_pack_k(
    const float* __restrict__ mask, unsigned int* __restrict__ mbits) {
  int row = blockIdx.x * 4 + (threadIdx.x >> 6);
  int lane = threadIdx.x & 63;
  if (row >= NWIN * NTOK) return;
  const float* mr = mask + (size_t)row * NTOK;
#pragma unroll
  for (int seg = 0; seg < 6; ++seg) {
    int j = seg * 64 + lane;
    bool allowed = (j < NTOK) ? (mr[j] == 0.0f) : false;
    unsigned long long bits = __ballot(allowed);
    if (lane == 0) mbits[(size_t)row * MBW + seg*2] = (unsigned)bits;
    if (lane == 1 && seg*2 + 1 < MBW) mbits[(size_t)row * MBW + seg*2 + 1] = (unsigned)(bits >> 32);
  }
}

// ---------------- MFMA GEMM: C[m,f] = sum_k A[m,k]*B[f,k] ----------------
// 128x128 tile, BK=32, 4 waves (2x2 of 64x64), 16x16x32 f16 MFMA, fp32 accum.
// LDS tiles k-major [kg][row][8] -> conflict-free b128 reads & writes.
// A_F32/B_F32: operand is fp32 in global, converted to fp16 during staging.
// EPI 0: packed qkv store (scale q cols f<384), fp16.  EPI 1: out = acc + bias, fp32.
template<int A_F32, int B_F32, int EPI>
__global__ __launch_bounds__(256) void gemm_mfma_k(
    const void* __restrict__ Av, const void* __restrict__ Bv,
    const float* __restrict__ bias, void* __restrict__ Cv) {
  __shared__ __half As[4 * 128 * 8];
  __shared__ __half Bs[4 * 128 * 8];
  const int tid  = threadIdx.x;
  const int lane = tid & 63, wave = tid >> 6;
  const int lr = lane & 15, lg = lane >> 4;
  const int wr = wave >> 1, wc = wave & 1;
  const int n0 = blockIdx.x * 128;
  const int m0 = blockIdx.y * 128;
  const int KD = 384;
  const int FDIM = (EPI == 0) ? QKVF : CDIM;

  f32x4 acc[4][4];
#pragma unroll
  for (int i = 0; i < 4; ++i)
#pragma unroll
    for (int j = 0; j < 4; ++j) acc[i][j] = (f32x4){0.f, 0.f, 0.f, 0.f};

  for (int k0 = 0; k0 < KD; k0 += 32) {
    __syncthreads();
    // stage A: 2 chunks (16 B) per thread, chunk c -> [kg=c>>7][row=c&127]
#pragma unroll
    for (int i = 0; i < 2; ++i) {
      int c = i * 256 + tid;
      int row = c & 127, kg = c >> 7;
      if (A_F32) {
        const float* gp = (const float*)Av + (size_t)(m0 + row) * KD + k0 + kg * 8;
        float4 fa = *(const float4*)gp;
        float4 fb = *(const float4*)(gp + 4);
        half8 hv;
        hv[0] = (_Float16)fa.x; hv[1] = (_Float16)fa.y; hv[2] = (_Float16)fa.z; hv[3] = (_Float16)fa.w;
        hv[4] = (_Float16)fb.x; hv[5] = (_Float16)fb.y; hv[6] = (_Float16)fb.z; hv[7] = (_Float16)fb.w;
        *(half8*)&As[c * 8] = hv;
      } else {
        const __half* gp = (const __half*)Av + (size_t)(m0 + row) * KD + k0 + kg * 8;
        *(half8*)&As[c * 8] = *(const half8*)gp;
      }
    }
    // stage B
#pragma unroll
    for (int i = 0; i < 2; ++i) {
      int c = i * 256 + tid;
      int row = c & 127, kg = c >> 7;
      if (B_F32) {
        const float* gp = (const float*)Bv + (size_t)(n0 + row) * KD + k0 + kg * 8;
        float4 fa = *(const float4*)gp;
        float4 fb = *(const float4*)(gp + 4);
        half8 hv;
        hv[0] = (_Float16)fa.x; hv[1] = (_Float16)fa.y; hv[2] = (_Float16)fa.z; hv[3] = (_Float16)fa.w;
        hv[4] = (_Float16)fb.x; hv[5] = (_Float16)fb.y; hv[6] = (_Float16)fb.z; hv[7] = (_Float16)fb.w;
        *(half8*)&Bs[c * 8] = hv;
      } else {
        const __half* gp = (const __half*)Bv + (size_t)(n0 + row) * KD + k0 + kg * 8;
        *(half8*)&Bs[c * 8] = *(const half8*)gp;
      }
    }
    __syncthreads();

    // fragments: lane (lr,lg) A[row=wr*64+mi*16+lr][k=lg*8..] = As[(lg*128+row)*8]
    half8 af[4], bf[4];
#pragma unroll
    for (int t = 0; t < 4; ++t) {
      af[t] = *(const half8*)&As[(lg * 128 + wr * 64 + t * 16 + lr) * 8];
      bf[t] = *(const half8*)&Bs[(lg * 128 + wc * 64 + t * 16 + lr) * 8];
    }
#pragma unroll
    for (int mi = 0; mi < 4; ++mi)
#pragma unroll
      for (int ni = 0; ni < 4; ++ni)
        acc[mi][ni] = __builtin_amdgcn_mfma_f32_16x16x32_f16(af[mi], bf[ni], acc[mi][ni], 0, 0, 0);
  }

  // epilogue: D row = wr*64+mi*16+lg*4+r, col = wc*64+ni*16+lr
#pragma unroll
  for (int mi = 0; mi < 4; ++mi) {
#pragma unroll
    for (int r = 0; r < 4; ++r) {
      int m = m0 + wr * 64 + mi * 16 + lg * 4 + r;
#pragma unroll
      for (int ni = 0; ni < 4; ++ni) {
        int f = n0 + wc * 64 + ni * 16 + lr;
        float v = acc[mi][ni][r];
        if (EPI == 0) {
          if (f < CDIM) v *= 0.17677669529663687f;   // q scale
          ((__half*)Cv)[(size_t)m * QKVF + f] = __float2half(v);
        } else {
          ((float*)Cv)[(size_t)m * CDIM + f] = v + bias[f];
        }
      }
    }
  }
  (void)FDIM;
}

// ---------------- MFMA attention: 1 block per (b,h), 8 waves ----------------
// reads packed qkvh[m][1152]: q at +0, k at +384, v at +768 (within token row), q pre-scaled
__global__ __launch_bounds__(512, 1) void attn_k(
    const __half* __restrict__ qkvh, const __half* __restrict__ bias16,
    const unsigned int* __restrict__ mbits, __half* __restrict__ av) {
  extern __shared__ __half smem[];
  __half* Ks = smem;                 // [NPAD][KSTR]
  __half* Vt = smem + LDS_K;         // [DH][VSTR]
  const int tid  = threadIdx.x;
  const int wave = tid >> 6, lane = tid & 63;
  const int lr   = lane & 15, lg = lane >> 4;
  __half* Pw = smem + LDS_K + LDS_V + wave * LDS_P;

  const int bh = blockIdx.x;
  const int b  = bh / NH, h = bh - b * NH;
  const int w  = b & (NWIN - 1);
  const size_t tbase = (size_t)b * NTOK;   // token row base
  const int hoff = h * DH;

  // stage K (rows >= NTOK zeroed)
  for (int idx = tid; idx < NPAD * 4; idx += 512) {
    int j = idx >> 2, off = (idx & 3) << 3;
    half8 val = {0,0,0,0,0,0,0,0};
    if (j < NTOK) val = *reinterpret_cast<const half8*>(&qkvh[(tbase + j) * QKVF + CDIM + hoff + off]);
    *reinterpret_cast<half8*>(&Ks[j * KSTR + off]) = val;
  }
  // stage V transposed (cols >= NTOK zeroed)
  for (int idx = tid; idx < NPAD * 4; idx += 512) {
    int j = idx >> 2, off = (idx & 3) << 3;
    if (j < NTOK) {
      union { float4 f; __half h[8]; } u;
      u.f = *reinterpret_cast<const float4*>(&qkvh[(tbase + j) * QKVF + 2 * CDIM + hoff + off]);
#pragma unroll
      for (int uu = 0; uu < 8; ++uu) Vt[(off + uu) * VSTR + j] = u.h[uu];
    } else {
#pragma unroll
      for (int uu = 0; uu < 8; ++uu) Vt[(off + uu) * VSTR + j] = __float2half(0.f);
    }
  }
  __syncthreads();

  const __half* bias_h = bias16 + (size_t)h * NN;
  const unsigned int* mb_w = mbits + (size_t)w * NTOK * MBW;

  for (int i0 = wave * 16; i0 < NPAD; i0 += 128) {
    int qrow = min(i0 + lr, NTOK - 1);
    half8 qa = *reinterpret_cast<const half8*>(&qkvh[(tbase + qrow) * QKVF + hoff + lg * 8]);

    f32x4 s[22];
    const f32x4 zf = {0.f, 0.f, 0.f, 0.f};
#pragma unroll
    for (int jt = 0; jt < 22; ++jt) {
      half8 kb = *reinterpret_cast<const half8*>(&Ks[(jt * 16 + lr) * KSTR + lg * 8]);
      s[jt] = __builtin_amdgcn_mfma_f32_16x16x32_f16(qa, kb, zf, 0, 0, 0);
    }

    int il[4];
#pragma unroll
    for (int r = 0; r < 4; ++r) il[r] = min(i0 + lg * 4 + r, NTOK - 1);

#pragma unroll
    for (int jt = 0; jt < 22; ++jt) {
      int j = jt * 16 + lr;
      bool vj = (jt < 21) || (lr < 7);          // j < 343
      int jl = vj ? j : (NTOK - 1);
      unsigned sh = (unsigned)(((jt & 1) << 4) + lr);
#pragma unroll
      for (int r = 0; r < 4; ++r) {
        float bm = __half2float(bias_h[(size_t)il[r] * NTOK + jl]);
        unsigned mwv = mb_w[il[r] * MBW + (jt >> 1)];
        float madd = ((mwv >> sh) & 1u) ? 0.f : -100.f;
        float val = s[jt][r] + bm + madd;
        s[jt][r] = vj ? val : -1e30f;
      }
    }

    float mx[4] = {-1e30f, -1e30f, -1e30f, -1e30f};
#pragma unroll
    for (int jt = 0; jt < 22; ++jt)
#pragma unroll
      for (int r = 0; r < 4; ++r) mx[r] = fmaxf(mx[r], s[jt][r]);
#pragma unroll
    for (int off = 1; off <= 8; off <<= 1)
#pragma unroll
      for (int r = 0; r < 4; ++r) mx[r] = fmaxf(mx[r], __shfl_xor(mx[r], off));
    float sm[4] = {0.f, 0.f, 0.f, 0.f};
#pragma unroll
    for (int jt = 0; jt < 22; ++jt)
#pragma unroll
      for (int r = 0; r < 4; ++r) {
        float p = __expf(s[jt][r] - mx[r]);
        s[jt][r] = p;
        sm[r] += p;
      }
#pragma unroll
    for (int off = 1; off <= 8; off <<= 1)
#pragma unroll
      for (int r = 0; r < 4; ++r) sm[r] += __shfl_xor(sm[r], off);

#pragma unroll
    for (int jt = 0; jt < 22; ++jt)
#pragma unroll
      for (int r = 0; r < 4; ++r)
        Pw[(lg * 4 + r) * PSTR + jt * 16 + lr] = __float2half(s[jt][r]);
    asm volatile("s_waitcnt lgkmcnt(0)" ::: "memory");
    __builtin_amdgcn_sched_barrier(0);

    f32x4 o0 = {0.f, 0.f, 0.f, 0.f}, o1 = {0.f, 0.f, 0.f, 0.f};
#pragma unroll
    for (int kt = 0; kt < 11; ++kt) {
      half8 pa  = *reinterpret_cast<const half8*>(&Pw[lr * PSTR + kt * 32 + lg * 8]);
      half8 vb0 = *reinterpret_cast<const half8*>(&Vt[lr * VSTR + kt * 32 + lg * 8]);
      half8 vb1 = *reinterpret_cast<const half8*>(&Vt[(16 + lr) * VSTR + kt * 32 + lg * 8]);
      o0 = __builtin_amdgcn_mfma_f32_16x16x32_f16(pa, vb0, o0, 0, 0, 0);
      o1 = __builtin_amdgcn_mfma_f32_16x16x32_f16(pa, vb1, o1, 0, 0, 0);
    }

#pragma unroll
    for (int r = 0; r < 4; ++r) {
      int i = i0 + lg * 4 + r;
      if (i < NTOK) {
        float inv = 1.f / sm[r];
        size_t ob = ((size_t)b * NTOK + i) * CDIM + hoff;
        av[ob + lr]      = __float2half(o0[r] * inv);
        av[ob + 16 + lr] = __float2half(o1[r] * inv);
      }
    }
  }
}

extern "C" void kernel_launch(void* const* d_in, const int* in_sizes, int n_in,
                              void* d_out, int out_size, void* d_ws, size_t ws_size,
                              hipStream_t stream) {
  const float* x          = (const float*)d_in[0];
  const float* mask       = (const float*)d_in[4];
  const float* w_qkv      = (const float*)d_in[6];
  const float* bias_table = (const float*)d_in[7];
  const float* w_proj     = (const float*)d_in[8];
  const float* b_proj     = (const float*)d_in[9];
  const int*   rel_index  = (const int*)d_in[10];
  float* out = (float*)d_out;

  // ws (byte-identical total to round 3's proven 138.18 MB):
  // qkvh [MTOK][1152] fp16 + av [MTOK][384] fp16 + bias16 [12][NN] + mbits
  __half* qkvh   = (__half*)d_ws;
  __half* avb    = qkvh + (size_t)MTOK * QKVF;
  __half* bias16 = avb + (size_t)MTOK * CDIM;
  unsigned int* mbits = (unsigned int*)(bias16 + (size_t)NH * NN);

  mask_pack_k<<<(NWIN * NTOK + 3) / 4, 256, 0, stream>>>(mask, mbits);
  bias_expand_k<<<(NN + 255) / 256, 256, 0, stream>>>(rel_index, bias_table, bias16);

  // QKV: A = x (fp32), B = w_qkv (fp32), C = packed qkvh (fp16, q scaled)
  gemm_mfma_k<1, 1, 0><<<dim3(QKVF / 128, MTOK / 128), 256, 0, stream>>>(
      x, w_qkv, nullptr, qkvh);

  (void)hipFuncSetAttribute((const void*)attn_k,
                            hipFuncAttributeMaxDynamicSharedMemorySize, LDS_TOT * 2);
  attn_k<<<BATCH * NH, 512, LDS_TOT * 2, stream>>>(qkvh, bias16, mbits, avb);

  // proj: A = av (fp16), B = w_proj (fp32), C = out (fp32 + bias)
  gemm_mfma_k<0, 1, 1><<<dim3(CDIM / 128, MTOK / 128), 256, 0, stream>>>(
      avb, w_proj, b_proj, out);
}

// Round 5
// 321.009 us; speedup vs baseline: 7.2725x; 1.2148x over previous
//
#include <hip/hip_runtime.h>
#include <hip/hip_fp16.h>
#include <math.h>

#define BATCH 128
#define NTOK  343
#define NPAD  352
#define CDIM  384
#define NH    12
#define DH    32
#define NWIN  32
#define MTOK  (BATCH*NTOK)   // 43904
#define NN    (NTOK*NTOK)    // 117649
#define QKVF  (3*CDIM)       // 1152
#define KSTR  40             // attn K LDS row stride (halves)
#define VSTR  360
#define PSTR  360
#define MBW   11             // u32 words per packed mask row

typedef float    f32x4 __attribute__((ext_vector_type(4)));
typedef _Float16 half8 __attribute__((ext_vector_type(8)));

#define LDS_K   (NPAD*KSTR)
#define LDS_V   (DH*VSTR)
#define LDS_P   (16*PSTR)
#define LDS_TOT (LDS_K + LDS_V + 8*LDS_P)   // 143360 B

// async global->LDS, 16B per lane; LDS dest = wave-uniform base + lane*16
__device__ __forceinline__ void gl2lds16(const __half* g, __half* l) {
  __builtin_amdgcn_global_load_lds(
      (const __attribute__((address_space(1))) void*)g,
      (__attribute__((address_space(3))) void*)l,
      16, 0, 0);
}

// ---------------- fp32 -> fp16 convert (8 elems/thread) ----------------
__global__ __launch_bounds__(256) void cvt_f16_k(
    const float* __restrict__ in, __half* __restrict__ out, int n) {
  int i = (blockIdx.x * 256 + threadIdx.x) * 8;
  if (i >= n) return;
  float4 a = *(const float4*)&in[i];
  float4 b = *(const float4*)&in[i + 4];
  half8 h;
  h[0] = (_Float16)a.x; h[1] = (_Float16)a.y; h[2] = (_Float16)a.z; h[3] = (_Float16)a.w;
  h[4] = (_Float16)b.x; h[5] = (_Float16)b.y; h[6] = (_Float16)b.z; h[7] = (_Float16)b.w;
  *(half8*)&out[i] = h;
}

// ---------------- bias gather to fp16 dense [h][i][j] ----------------
__global__ __launch_bounds__(256) void bias_expand_k(
    const int* __restrict__ rel_index, const float* __restrict__ table,
    __half* __restrict__ bias16) {
  int ij = blockIdx.x * 256 + threadIdx.x;
  if (ij >= NN) return;
  int idx = rel_index[ij];
#pragma unroll
  for (int hh = 0; hh < NH; ++hh)
    bias16[(size_t)hh * NN + ij] = __float2half(table[idx * NH + hh]);
}

// ---------------- mask bit-pack: bit=1 where mask==0 (allowed) ----------------
__global__ __launch_bounds__(256) void mask_pack_k(
    const float* __restrict__ mask, unsigned int* __restrict__ mbits) {
  int row = blockIdx.x * 4 + (threadIdx.x >> 6);
  int lane = threadIdx.x & 63;
  if (row >= NWIN * NTOK) return;
  const float* mr = mask + (size_t)row * NTOK;
#pragma unroll
  for (int seg = 0; seg < 6; ++seg) {
    int j = seg * 64 + lane;
    bool allowed = (j < NTOK) ? (mr[j] == 0.0f) : false;
    unsigned long long bits = __ballot(allowed);
    if (lane == 0) mbits[(size_t)row * MBW + seg*2] = (unsigned)bits;
    if (lane == 1 && seg*2 + 1 < MBW) mbits[(size_t)row * MBW + seg*2 + 1] = (unsigned)(bits >> 32);
  }
}

// ---------------- MFMA GEMM (all-fp16 inputs, global_load_lds staging) --------
// C[m,f] = sum_k A[m,k]*B[f,k]; 128x128 tile, BK=32, 4 waves, m97 2-barrier loop.
// LDS k-major: chunk c = kg*128+row  ->  lds[c*8..c*8+7] = op[row][kg*8..+7]
// EPI 0: packed qkv fp16 store (scale cols f<384).  EPI 1: fp32 out = acc+bias.
template<int EPI>
__global__ __launch_bounds__(256) void gemm_mfma_k(
    const __half* __restrict__ Ah, const __half* __restrict__ Bh,
    const float* __restrict__ bias, void* __restrict__ Cv) {
  __shared__ __half As[128 * 32];
  __shared__ __half Bs[128 * 32];
  const int tid  = threadIdx.x;
  const int lane = tid & 63, wave = tid >> 6;
  const int lr = lane & 15, lg = lane >> 4;
  const int wr = wave >> 1, wc = wave & 1;
  const int n0 = blockIdx.x * 128;
  const int m0 = blockIdx.y * 128;
  const int KD = 384;

  f32x4 acc[4][4];
#pragma unroll
  for (int i = 0; i < 4; ++i)
#pragma unroll
    for (int j = 0; j < 4; ++j) acc[i][j] = (f32x4){0.f, 0.f, 0.f, 0.f};

  for (int k0 = 0; k0 < KD; k0 += 32) {
    // issue async staging: per wave 2 chunks-of-64 for A, 2 for B
#pragma unroll
    for (int i = 0; i < 2; ++i) {
      int cb = wave * 128 + i * 64;          // wave-uniform chunk base
      int c  = cb + lane;
      int row = c & 127, kg = c >> 7;
      gl2lds16(&Ah[(size_t)(m0 + row) * KD + k0 + kg * 8], &As[cb * 8]);
      gl2lds16(&Bh[(size_t)(n0 + row) * KD + k0 + kg * 8], &Bs[cb * 8]);
    }
    __syncthreads();   // vmcnt(0) drain + barrier: tile ready

    half8 af[4], bf[4];
#pragma unroll
    for (int t = 0; t < 4; ++t) {
      af[t] = *(const half8*)&As[(lg * 128 + wr * 64 + t * 16 + lr) * 8];
      bf[t] = *(const half8*)&Bs[(lg * 128 + wc * 64 + t * 16 + lr) * 8];
    }
#pragma unroll
    for (int mi = 0; mi < 4; ++mi)
#pragma unroll
      for (int ni = 0; ni < 4; ++ni)
        acc[mi][ni] = __builtin_amdgcn_mfma_f32_16x16x32_f16(af[mi], bf[ni], acc[mi][ni], 0, 0, 0);
    __syncthreads();   // all reads done before next overwrite
  }

  // epilogue: D row = wr*64+mi*16+lg*4+r, col = wc*64+ni*16+lr
#pragma unroll
  for (int mi = 0; mi < 4; ++mi) {
#pragma unroll
    for (int r = 0; r < 4; ++r) {
      int m = m0 + wr * 64 + mi * 16 + lg * 4 + r;
#pragma unroll
      for (int ni = 0; ni < 4; ++ni) {
        int f = n0 + wc * 64 + ni * 16 + lr;
        float v = acc[mi][ni][r];
        if (EPI == 0) {
          if (f < CDIM) v *= 0.17677669529663687f;   // q scale
          ((__half*)Cv)[(size_t)m * QKVF + f] = __float2half(v);
        } else {
          ((float*)Cv)[(size_t)m * CDIM + f] = v + bias[f];
        }
      }
    }
  }
}

// ---------------- MFMA attention (unchanged from round 4) ----------------
__global__ __launch_bounds__(512, 1) void attn_k(
    const __half* __restrict__ qkvh, const __half* __restrict__ bias16,
    const unsigned int* __restrict__ mbits, __half* __restrict__ av) {
  extern __shared__ __half smem[];
  __half* Ks = smem;                 // [NPAD][KSTR]
  __half* Vt = smem + LDS_K;         // [DH][VSTR]
  const int tid  = threadIdx.x;
  const int wave = tid >> 6, lane = tid & 63;
  const int lr   = lane & 15, lg = lane >> 4;
  __half* Pw = smem + LDS_K + LDS_V + wave * LDS_P;

  const int bh = blockIdx.x;
  const int b  = bh / NH, h = bh - b * NH;
  const int w  = b & (NWIN - 1);
  const size_t tbase = (size_t)b * NTOK;
  const int hoff = h * DH;

  for (int idx = tid; idx < NPAD * 4; idx += 512) {
    int j = idx >> 2, off = (idx & 3) << 3;
    half8 val = {0,0,0,0,0,0,0,0};
    if (j < NTOK) val = *reinterpret_cast<const half8*>(&qkvh[(tbase + j) * QKVF + CDIM + hoff + off]);
    *reinterpret_cast<half8*>(&Ks[j * KSTR + off]) = val;
  }
  for (int idx = tid; idx < NPAD * 4; idx += 512) {
    int j = idx >> 2, off = (idx & 3) << 3;
    if (j < NTOK) {
      union { float4 f; __half h[8]; } u;
      u.f = *reinterpret_cast<const float4*>(&qkvh[(tbase + j) * QKVF + 2 * CDIM + hoff + off]);
#pragma unroll
      for (int uu = 0; uu < 8; ++uu) Vt[(off + uu) * VSTR + j] = u.h[uu];
    } else {
#pragma unroll
      for (int uu = 0; uu < 8; ++uu) Vt[(off + uu) * VSTR + j] = __float2half(0.f);
    }
  }
  __syncthreads();

  const __half* bias_h = bias16 + (size_t)h * NN;
  const unsigned int* mb_w = mbits + (size_t)w * NTOK * MBW;

  for (int i0 = wave * 16; i0 < NPAD; i0 += 128) {
    int qrow = min(i0 + lr, NTOK - 1);
    half8 qa = *reinterpret_cast<const half8*>(&qkvh[(tbase + qrow) * QKVF + hoff + lg * 8]);

    f32x4 s[22];
    const f32x4 zf = {0.f, 0.f, 0.f, 0.f};
#pragma unroll
    for (int jt = 0; jt < 22; ++jt) {
      half8 kb = *reinterpret_cast<const half8*>(&Ks[(jt * 16 + lr) * KSTR + lg * 8]);
      s[jt] = __builtin_amdgcn_mfma_f32_16x16x32_f16(qa, kb, zf, 0, 0, 0);
    }

    int il[4];
#pragma unroll
    for (int r = 0; r < 4; ++r) il[r] = min(i0 + lg * 4 + r, NTOK - 1);

#pragma unroll
    for (int jt = 0; jt < 22; ++jt) {
      int j = jt * 16 + lr;
      bool vj = (jt < 21) || (lr < 7);          // j < 343
      int jl = vj ? j : (NTOK - 1);
      unsigned sh = (unsigned)(((jt & 1) << 4) + lr);
#pragma unroll
      for (int r = 0; r < 4; ++r) {
        float bm = __half2float(bias_h[(size_t)il[r] * NTOK + jl]);
        unsigned mwv = mb_w[il[r] * MBW + (jt >> 1)];
        float madd = ((mwv >> sh) & 1u) ? 0.f : -100.f;
        float val = s[jt][r] + bm + madd;
        s[jt][r] = vj ? val : -1e30f;
      }
    }

    float mx[4] = {-1e30f, -1e30f, -1e30f, -1e30f};
#pragma unroll
    for (int jt = 0; jt < 22; ++jt)
#pragma unroll
      for (int r = 0; r < 4; ++r) mx[r] = fmaxf(mx[r], s[jt][r]);
#pragma unroll
    for (int off = 1; off <= 8; off <<= 1)
#pragma unroll
      for (int r = 0; r < 4; ++r) mx[r] = fmaxf(mx[r], __shfl_xor(mx[r], off));
    float sm[4] = {0.f, 0.f, 0.f, 0.f};
#pragma unroll
    for (int jt = 0; jt < 22; ++jt)
#pragma unroll
      for (int r = 0; r < 4; ++r) {
        float p = __expf(s[jt][r] - mx[r]);
        s[jt][r] = p;
        sm[r] += p;
      }
#pragma unroll
    for (int off = 1; off <= 8; off <<= 1)
#pragma unroll
      for (int r = 0; r < 4; ++r) sm[r] += __shfl_xor(sm[r], off);

#pragma unroll
    for (int jt = 0; jt < 22; ++jt)
#pragma unroll
      for (int r = 0; r < 4; ++r)
        Pw[(lg * 4 + r) * PSTR + jt * 16 + lr] = __float2half(s[jt][r]);
    asm volatile("s_waitcnt lgkmcnt(0)" ::: "memory");
    __builtin_amdgcn_sched_barrier(0);

    f32x4 o0 = {0.f, 0.f, 0.f, 0.f}, o1 = {0.f, 0.f, 0.f, 0.f};
#pragma unroll
    for (int kt = 0; kt < 11; ++kt) {
      half8 pa  = *reinterpret_cast<const half8*>(&Pw[lr * PSTR + kt * 32 + lg * 8]);
      half8 vb0 = *reinterpret_cast<const half8*>(&Vt[lr * VSTR + kt * 32 + lg * 8]);
      half8 vb1 = *reinterpret_cast<const half8*>(&Vt[(16 + lr) * VSTR + kt * 32 + lg * 8]);
      o0 = __builtin_amdgcn_mfma_f32_16x16x32_f16(pa, vb0, o0, 0, 0, 0);
      o1 = __builtin_amdgcn_mfma_f32_16x16x32_f16(pa, vb1, o1, 0, 0, 0);
    }

#pragma unroll
    for (int r = 0; r < 4; ++r) {
      int i = i0 + lg * 4 + r;
      if (i < NTOK) {
        float inv = 1.f / sm[r];
        size_t ob = ((size_t)b * NTOK + i) * CDIM + hoff;
        av[ob + lr]      = __float2half(o0[r] * inv);
        av[ob + 16 + lr] = __float2half(o1[r] * inv);
      }
    }
  }
}

extern "C" void kernel_launch(void* const* d_in, const int* in_sizes, int n_in,
                              void* d_out, int out_size, void* d_ws, size_t ws_size,
                              hipStream_t stream) {
  const float* x          = (const float*)d_in[0];
  const float* mask       = (const float*)d_in[4];
  const float* w_qkv      = (const float*)d_in[6];
  const float* bias_table = (const float*)d_in[7];
  const float* w_proj     = (const float*)d_in[8];
  const float* b_proj     = (const float*)d_in[9];
  const int*   rel_index  = (const int*)d_in[10];
  float* out = (float*)d_out;

  // ws layout (139.35 MB, under round-2's proven 140.5 MB):
  //   qkvh [MTOK][1152] fp16
  //   avb  [MTOK][384]  fp16   (aliased as xh during QKV: x dead before attn writes)
  //   bias16 [12][NN] fp16, mbits, wqkvh [1152][384] fp16, wprojh [384][384] fp16
  __half* qkvh   = (__half*)d_ws;
  __half* avb    = qkvh + (size_t)MTOK * QKVF;
  __half* xh     = avb;                                  // alias
  __half* bias16 = avb + (size_t)MTOK * CDIM;
  unsigned int* mbits = (unsigned int*)(bias16 + (size_t)NH * NN);
  __half* wqkvh  = (__half*)(mbits + (size_t)NWIN * NTOK * MBW);
  __half* wprojh = wqkvh + (size_t)QKVF * CDIM;

  const int NX = MTOK * CDIM;        // 16,859,136
  const int NWQ = QKVF * CDIM;       // 442,368
  const int NWP = CDIM * CDIM;       // 147,456
  cvt_f16_k<<<NX / 8 / 256, 256, 0, stream>>>(x, xh, NX);
  cvt_f16_k<<<NWQ / 8 / 256, 256, 0, stream>>>(w_qkv, wqkvh, NWQ);
  cvt_f16_k<<<NWP / 8 / 256, 256, 0, stream>>>(w_proj, wprojh, NWP);
  mask_pack_k<<<(NWIN * NTOK + 3) / 4, 256, 0, stream>>>(mask, mbits);
  bias_expand_k<<<(NN + 255) / 256, 256, 0, stream>>>(rel_index, bias_table, bias16);

  // QKV: A = xh, B = wqkvh, C = packed qkvh (fp16, q scaled)
  gemm_mfma_k<0><<<dim3(QKVF / 128, MTOK / 128), 256, 0, stream>>>(
      xh, wqkvh, nullptr, qkvh);

  (void)hipFuncSetAttribute((const void*)attn_k,
                            hipFuncAttributeMaxDynamicSharedMemorySize, LDS_TOT * 2);
  attn_k<<<BATCH * NH, 512, LDS_TOT * 2, stream>>>(qkvh, bias16, mbits, avb);

  // proj: A = avb (fp16), B = wprojh, C = out (fp32 + bias)
  gemm_mfma_k<1><<<dim3(CDIM / 128, MTOK / 128), 256, 0, stream>>>(
      avb, wprojh, b_proj, out);
}